// Round 7
// baseline (2805.176 us; speedup 1.0000x reference)
//
#include <hip/hip_runtime.h>
#include <math.h>

// GatedDeltaBlock on MI355X (gfx950). Round 7.
// BUG FIX: gate path applied SiLU twice (GEMM epi-0 stores silu(h@gw), and
// gate_kernel applied silu again). This was the precision-independent 0.219
// absmax shared bit-identically by rounds 1/4/6. gate_kernel now uses the
// staged gate value directly. Numerics otherwise as round 6 (split-bf16
// q/k/v projections, fp32 beta/g, fp32 scan).

#define B_ 4
#define T_ 2048
#define D_ 1024
#define H_ 8
#define HD_ 128
#define RES_SCALE 0.5f

typedef __bf16 bf16x8 __attribute__((ext_vector_type(8)));
typedef float f32x4 __attribute__((ext_vector_type(4)));

__device__ __forceinline__ float bf2f(unsigned short u) {
    union { unsigned int i; float f; } w; w.i = ((unsigned int)u) << 16; return w.f;
}
__device__ __forceinline__ unsigned short f2bf(float f) {
    unsigned int x = __float_as_uint(f);
    x += 0x7fffu + ((x >> 16) & 1u);   // RNE
    return (unsigned short)(x >> 16);
}
__device__ __forceinline__ float sigm(float x) { return 1.f / (1.f + __expf(-x)); }

// ---------------- f32 -> bf16 (single) ----------------
__global__ __launch_bounds__(256) void cvt_kernel(const float* __restrict__ src,
                                                  unsigned short* __restrict__ dst, int n4) {
    int i = blockIdx.x * 256 + threadIdx.x;
    if (i < n4) {
        float4 v = ((const float4*)src)[i];
        ushort4 o;
        o.x = f2bf(v.x); o.y = f2bf(v.y); o.z = f2bf(v.z); o.w = f2bf(v.w);
        ((ushort4*)dst)[i] = o;
    }
}

// ---------------- f32 -> bf16 hi+lo planes ----------------
__global__ __launch_bounds__(256) void cvt2_kernel(const float* __restrict__ src,
                                                   unsigned short* __restrict__ hi,
                                                   unsigned short* __restrict__ lo, int n4) {
    int i = blockIdx.x * 256 + threadIdx.x;
    if (i < n4) {
        float4 v = ((const float4*)src)[i];
        ushort4 h, l;
        h.x = f2bf(v.x); l.x = f2bf(v.x - bf2f(h.x));
        h.y = f2bf(v.y); l.y = f2bf(v.y - bf2f(h.y));
        h.z = f2bf(v.z); l.z = f2bf(v.z - bf2f(h.z));
        h.w = f2bf(v.w); l.w = f2bf(v.w - bf2f(h.w));
        ((ushort4*)hi)[i] = h;
        ((ushort4*)lo)[i] = l;
    }
}

// ---------------- RMSNorm (D=1024), f32 in -> bf16 hi (+ optional lo) ----------------
__global__ __launch_bounds__(256) void rmsnorm_kernel(const float* __restrict__ x,
                                                      const float* __restrict__ w,
                                                      unsigned short* __restrict__ outh,
                                                      unsigned short* __restrict__ outl) {
    int row = blockIdx.x;
    int tid = threadIdx.x;
    float4 v = ((const float4*)(x + (size_t)row * D_))[tid];
    float ss = v.x * v.x + v.y * v.y + v.z * v.z + v.w * v.w;
    #pragma unroll
    for (int m = 1; m < 64; m <<= 1) ss += __shfl_xor(ss, m);
    __shared__ float red[4];
    if ((tid & 63) == 0) red[tid >> 6] = ss;
    __syncthreads();
    float tot = red[0] + red[1] + red[2] + red[3];
    float sc = rsqrtf(tot * (1.f / D_) + 1e-6f);
    float4 wv = ((const float4*)w)[tid];
    float h0 = v.x * sc * wv.x, h1 = v.y * sc * wv.y;
    float h2 = v.z * sc * wv.z, h3 = v.w * sc * wv.w;
    ushort4 oh;
    oh.x = f2bf(h0); oh.y = f2bf(h1); oh.z = f2bf(h2); oh.w = f2bf(h3);
    ((ushort4*)(outh + (size_t)row * D_))[tid] = oh;
    if (outl) {
        ushort4 ol;
        ol.x = f2bf(h0 - bf2f(oh.x));
        ol.y = f2bf(h1 - bf2f(oh.y));
        ol.z = f2bf(h2 - bf2f(oh.z));
        ol.w = f2bf(h3 - bf2f(oh.w));
        ((ushort4*)(outl + (size_t)row * D_))[tid] = ol;
    }
}

// ---------------- plain bf16 MFMA GEMM ----------------
// 128x128 tile, BK=32, 256 thr. epi 0: silu->bf16. epi 1: f32 = aux + acc*0.5.
#define LDT 40
__global__ __launch_bounds__(256) void gemm_kernel(const unsigned short* __restrict__ A,
                                                   const unsigned short* __restrict__ Bm,
                                                   unsigned short* __restrict__ Obf,
                                                   float* __restrict__ Of,
                                                   const float* __restrict__ aux,
                                                   int N, int K, int epi) {
    __shared__ unsigned short As[128 * LDT];
    __shared__ unsigned short Bs[128 * LDT];
    int tid = threadIdx.x;
    int lane = tid & 63, wave = tid >> 6;
    int wm = (wave >> 1) * 64, wn = (wave & 1) * 64;
    int l15 = lane & 15, kg = lane >> 4;
    size_t gm = blockIdx.x, gn = blockIdx.y;

    int arow0 = tid >> 2, aseg = (tid & 3) * 8;
    int brow0 = tid >> 4, bc8 = (tid & 15) * 8;

    f32x4 acc[4][4] = {};

    for (int kt = 0; kt < K; kt += 32) {
        uint4 a0 = *(const uint4*)(A + (size_t)(gm * 128 + arow0) * K + kt + aseg);
        uint4 a1 = *(const uint4*)(A + (size_t)(gm * 128 + arow0 + 64) * K + kt + aseg);
        uint4 b0 = *(const uint4*)(Bm + (size_t)(kt + brow0) * N + gn * 128 + bc8);
        uint4 b1 = *(const uint4*)(Bm + (size_t)(kt + brow0 + 16) * N + gn * 128 + bc8);
        __syncthreads();
        *(uint4*)&As[arow0 * LDT + aseg] = a0;
        *(uint4*)&As[(arow0 + 64) * LDT + aseg] = a1;
        {
            unsigned int uu[4] = {b0.x, b0.y, b0.z, b0.w};
            #pragma unroll
            for (int p = 0; p < 4; p++) {
                Bs[(bc8 + 2 * p) * LDT + brow0] = (unsigned short)(uu[p] & 0xffffu);
                Bs[(bc8 + 2 * p + 1) * LDT + brow0] = (unsigned short)(uu[p] >> 16);
            }
            unsigned int vv[4] = {b1.x, b1.y, b1.z, b1.w};
            #pragma unroll
            for (int p = 0; p < 4; p++) {
                Bs[(bc8 + 2 * p) * LDT + brow0 + 16] = (unsigned short)(vv[p] & 0xffffu);
                Bs[(bc8 + 2 * p + 1) * LDT + brow0 + 16] = (unsigned short)(vv[p] >> 16);
            }
        }
        __syncthreads();
        bf16x8 af[4], bfr[4];
        #pragma unroll
        for (int m = 0; m < 4; m++)
            af[m] = *(const bf16x8*)&As[(wm + m * 16 + l15) * LDT + kg * 8];
        #pragma unroll
        for (int n = 0; n < 4; n++)
            bfr[n] = *(const bf16x8*)&Bs[(wn + n * 16 + l15) * LDT + kg * 8];
        #pragma unroll
        for (int m = 0; m < 4; m++)
            #pragma unroll
            for (int n = 0; n < 4; n++)
                acc[m][n] = __builtin_amdgcn_mfma_f32_16x16x32_bf16(af[m], bfr[n], acc[m][n], 0, 0, 0);
    }

    #pragma unroll
    for (int m = 0; m < 4; m++) {
        #pragma unroll
        for (int n = 0; n < 4; n++) {
            #pragma unroll
            for (int j = 0; j < 4; j++) {
                size_t row = gm * 128 + wm + m * 16 + kg * 4 + j;
                size_t col = gn * 128 + wn + n * 16 + l15;
                size_t idx = row * N + col;
                float v = acc[m][n][j];
                if (epi == 0) {
                    Obf[idx] = f2bf(v * sigm(v));
                } else {
                    Of[idx] = aux[idx] + v * RES_SCALE;
                }
            }
        }
    }
}

// ---------------- split-bf16 (hi+lo) 3-pass MFMA GEMM, silu -> f32 ----------------
// C = (Ah+Al)(Bh+Bl) ~= Ah*Bh + Ah*Bl + Al*Bh  (rel err ~2^-17, fp32-class)
__global__ __launch_bounds__(256) void gemm32_kernel(const unsigned short* __restrict__ Ah,
                                                     const unsigned short* __restrict__ Al,
                                                     const unsigned short* __restrict__ Bh,
                                                     const unsigned short* __restrict__ Bl,
                                                     float* __restrict__ Of,
                                                     int N, int K) {
    __shared__ unsigned short Ash[128 * LDT];
    __shared__ unsigned short Asl[128 * LDT];
    __shared__ unsigned short Bsh[128 * LDT];
    __shared__ unsigned short Bsl[128 * LDT];
    int tid = threadIdx.x;
    int lane = tid & 63, wave = tid >> 6;
    int wm = (wave >> 1) * 64, wn = (wave & 1) * 64;
    int l15 = lane & 15, kg = lane >> 4;
    size_t gm = blockIdx.x, gn = blockIdx.y;

    int arow0 = tid >> 2, aseg = (tid & 3) * 8;
    int brow0 = tid >> 4, bc8 = (tid & 15) * 8;

    f32x4 acc[4][4] = {};

    for (int kt = 0; kt < K; kt += 32) {
        size_t aoff0 = (size_t)(gm * 128 + arow0) * K + kt + aseg;
        size_t aoff1 = (size_t)(gm * 128 + arow0 + 64) * K + kt + aseg;
        size_t boff0 = (size_t)(kt + brow0) * N + gn * 128 + bc8;
        size_t boff1 = (size_t)(kt + brow0 + 16) * N + gn * 128 + bc8;
        uint4 a0h = *(const uint4*)(Ah + aoff0);
        uint4 a1h = *(const uint4*)(Ah + aoff1);
        uint4 a0l = *(const uint4*)(Al + aoff0);
        uint4 a1l = *(const uint4*)(Al + aoff1);
        uint4 b0h = *(const uint4*)(Bh + boff0);
        uint4 b1h = *(const uint4*)(Bh + boff1);
        uint4 b0l = *(const uint4*)(Bl + boff0);
        uint4 b1l = *(const uint4*)(Bl + boff1);
        __syncthreads();
        *(uint4*)&Ash[arow0 * LDT + aseg] = a0h;
        *(uint4*)&Ash[(arow0 + 64) * LDT + aseg] = a1h;
        *(uint4*)&Asl[arow0 * LDT + aseg] = a0l;
        *(uint4*)&Asl[(arow0 + 64) * LDT + aseg] = a1l;
        {
            unsigned int uu[4];
            uu[0] = b0h.x; uu[1] = b0h.y; uu[2] = b0h.z; uu[3] = b0h.w;
            #pragma unroll
            for (int p = 0; p < 4; p++) {
                Bsh[(bc8 + 2 * p) * LDT + brow0] = (unsigned short)(uu[p] & 0xffffu);
                Bsh[(bc8 + 2 * p + 1) * LDT + brow0] = (unsigned short)(uu[p] >> 16);
            }
            uu[0] = b1h.x; uu[1] = b1h.y; uu[2] = b1h.z; uu[3] = b1h.w;
            #pragma unroll
            for (int p = 0; p < 4; p++) {
                Bsh[(bc8 + 2 * p) * LDT + brow0 + 16] = (unsigned short)(uu[p] & 0xffffu);
                Bsh[(bc8 + 2 * p + 1) * LDT + brow0 + 16] = (unsigned short)(uu[p] >> 16);
            }
            uu[0] = b0l.x; uu[1] = b0l.y; uu[2] = b0l.z; uu[3] = b0l.w;
            #pragma unroll
            for (int p = 0; p < 4; p++) {
                Bsl[(bc8 + 2 * p) * LDT + brow0] = (unsigned short)(uu[p] & 0xffffu);
                Bsl[(bc8 + 2 * p + 1) * LDT + brow0] = (unsigned short)(uu[p] >> 16);
            }
            uu[0] = b1l.x; uu[1] = b1l.y; uu[2] = b1l.z; uu[3] = b1l.w;
            #pragma unroll
            for (int p = 0; p < 4; p++) {
                Bsl[(bc8 + 2 * p) * LDT + brow0 + 16] = (unsigned short)(uu[p] & 0xffffu);
                Bsl[(bc8 + 2 * p + 1) * LDT + brow0 + 16] = (unsigned short)(uu[p] >> 16);
            }
        }
        __syncthreads();
        bf16x8 afh[4], afl[4], bfh[4], bfl[4];
        #pragma unroll
        for (int m = 0; m < 4; m++) {
            afh[m] = *(const bf16x8*)&Ash[(wm + m * 16 + l15) * LDT + kg * 8];
            afl[m] = *(const bf16x8*)&Asl[(wm + m * 16 + l15) * LDT + kg * 8];
        }
        #pragma unroll
        for (int n = 0; n < 4; n++) {
            bfh[n] = *(const bf16x8*)&Bsh[(wn + n * 16 + l15) * LDT + kg * 8];
            bfl[n] = *(const bf16x8*)&Bsl[(wn + n * 16 + l15) * LDT + kg * 8];
        }
        #pragma unroll
        for (int m = 0; m < 4; m++) {
            #pragma unroll
            for (int n = 0; n < 4; n++) {
                acc[m][n] = __builtin_amdgcn_mfma_f32_16x16x32_bf16(afh[m], bfh[n], acc[m][n], 0, 0, 0);
                acc[m][n] = __builtin_amdgcn_mfma_f32_16x16x32_bf16(afh[m], bfl[n], acc[m][n], 0, 0, 0);
                acc[m][n] = __builtin_amdgcn_mfma_f32_16x16x32_bf16(afl[m], bfh[n], acc[m][n], 0, 0, 0);
            }
        }
    }

    #pragma unroll
    for (int m = 0; m < 4; m++) {
        #pragma unroll
        for (int n = 0; n < 4; n++) {
            #pragma unroll
            for (int j = 0; j < 4; j++) {
                size_t row = gm * 128 + wm + m * 16 + kg * 4 + j;
                size_t col = gn * 128 + wn + n * 16 + l15;
                float v = acc[m][n][j];
                Of[row * N + col] = v * sigm(v);
            }
        }
    }
}

// ---------------- beta / g projections from fp32 h (hi+lo) ----------------
__global__ __launch_bounds__(256) void smallproj_kernel(const unsigned short* __restrict__ hh,
                                                        const unsigned short* __restrict__ hl,
                                                        const float* __restrict__ bw,
                                                        const float* __restrict__ aw,
                                                        const float* __restrict__ A_log,
                                                        const float* __restrict__ dt_bias,
                                                        float* __restrict__ beta,
                                                        float* __restrict__ g) {
    int row = blockIdx.x;
    int tid = threadIdx.x;
    int out = tid >> 4, part = tid & 15;   // 16 outputs x 16 partials
    int head = out & 7;
    const float* W = (out < 8) ? bw : aw;
    const unsigned short* hrh = hh + (size_t)row * D_ + part * 64;
    const unsigned short* hrl = hl + (size_t)row * D_ + part * 64;
    float s = 0.f;
    #pragma unroll
    for (int j8 = 0; j8 < 8; j8++) {
        uint4 uh = *(const uint4*)(hrh + j8 * 8);
        uint4 ul = *(const uint4*)(hrl + j8 * 8);
        unsigned int ah[4] = {uh.x, uh.y, uh.z, uh.w};
        unsigned int al[4] = {ul.x, ul.y, ul.z, ul.w};
        #pragma unroll
        for (int p = 0; p < 4; p++) {
            int k = part * 64 + j8 * 8 + 2 * p;
            float v0 = bf2f((unsigned short)(ah[p] & 0xffffu)) + bf2f((unsigned short)(al[p] & 0xffffu));
            float v1 = bf2f((unsigned short)(ah[p] >> 16)) + bf2f((unsigned short)(al[p] >> 16));
            s += v0 * W[(size_t)k * H_ + head];
            s += v1 * W[(size_t)(k + 1) * H_ + head];
        }
    }
    s += __shfl_xor(s, 1); s += __shfl_xor(s, 2); s += __shfl_xor(s, 4); s += __shfl_xor(s, 8);
    if (part == 0) {
        if (out < 8) {
            beta[(size_t)row * H_ + head] = sigm(s);
        } else {
            float xx = s + dt_bias[head];
            float sp = (xx > 20.f) ? xx : log1pf(expf(xx));
            g[(size_t)row * H_ + head] = -expf(A_log[head]) * sp;
        }
    }
}

// ---------------- l2norm over HD=128, in-place on f32 ----------------
__global__ __launch_bounds__(256) void l2norm_kernel(float* __restrict__ qk) {
    int row = blockIdx.x * 4 + (threadIdx.x >> 6);
    int lane = threadIdx.x & 63;
    float* r = qk + (size_t)row * HD_ + lane * 2;
    float2 v = *(const float2*)r;
    float ss = v.x * v.x + v.y * v.y;
    #pragma unroll
    for (int m = 1; m < 64; m <<= 1) ss += __shfl_xor(ss, m);
    float sc = rsqrtf(ss + 1e-6f);
    float2 o = {v.x * sc, v.y * sc};
    *(float2*)r = o;
}

// ---------------- recurrent scan (fp32) ----------------
#define CH 32
__global__ __launch_bounds__(512) void scan_kernel(const float* __restrict__ q,
                                                   const float* __restrict__ k,
                                                   const float* __restrict__ v,
                                                   const float* __restrict__ beta,
                                                   const float* __restrict__ g,
                                                   float* __restrict__ o,
                                                   float* __restrict__ Sf) {
    int bh = blockIdx.x >> 1;
    int b = bh >> 3, h = bh & 7;
    int cb = (blockIdx.x & 1) * 64;
    int tid = threadIdx.x;
    int wave = tid >> 6, lane = tid & 63;
    int col = cb + wave * 8 + (lane & 7);
    int oct = lane >> 3;
    int dk0 = oct * 16;

    __shared__ float ks[2][CH][HD_];
    __shared__ float qs[2][CH][HD_];
    __shared__ float vs[2][CH][HD_];
    __shared__ float egs[2][CH];
    __shared__ float bes[2][CH];

    float S[16];
    #pragma unroll
    for (int j = 0; j < 16; j++) S[j] = 0.f;

    int sstep = tid >> 4;          // 0..31
    int sd = (tid & 15) * 8;       // 0..120

    auto stage = [&](int c, int buf) {
        size_t gbase = ((size_t)(b * T_ + c * CH + sstep)) * D_ + h * HD_ + sd;
        float4 q0 = *(const float4*)(q + gbase);
        float4 q1 = *(const float4*)(q + gbase + 4);
        float4 k0 = *(const float4*)(k + gbase);
        float4 k1 = *(const float4*)(k + gbase + 4);
        float4 v0 = *(const float4*)(v + gbase);
        float4 v1 = *(const float4*)(v + gbase + 4);
        *(float4*)&qs[buf][sstep][sd] = q0;
        *(float4*)&qs[buf][sstep][sd + 4] = q1;
        *(float4*)&ks[buf][sstep][sd] = k0;
        *(float4*)&ks[buf][sstep][sd + 4] = k1;
        *(float4*)&vs[buf][sstep][sd] = v0;
        *(float4*)&vs[buf][sstep][sd + 4] = v1;
        if (tid < CH) {
            egs[buf][tid] = expf(g[(size_t)(b * T_ + c * CH + tid) * H_ + h]);
        } else if (tid < 2 * CH) {
            bes[buf][tid - CH] = beta[(size_t)(b * T_ + c * CH + (tid - CH)) * H_ + h];
        }
    };

    auto computeC = [&](int c, int buf) {
        for (int s = 0; s < CH; s++) {
            float eg = egs[buf][s];
            float be = bes[buf][s];
            float vv = vs[buf][s][col];
            float4 kk[4];
            float kr = 0.f;
            #pragma unroll
            for (int j4 = 0; j4 < 4; j4++) {
                kk[j4] = *(const float4*)&ks[buf][s][dk0 + j4 * 4];
                kr += kk[j4].x * S[j4 * 4 + 0] + kk[j4].y * S[j4 * 4 + 1]
                    + kk[j4].z * S[j4 * 4 + 2] + kk[j4].w * S[j4 * 4 + 3];
            }
            kr += __shfl_xor(kr, 8);
            kr += __shfl_xor(kr, 16);
            kr += __shfl_xor(kr, 32);
            float u = be * (vv - eg * kr);
            float4 oa = {0.f, 0.f, 0.f, 0.f};
            #pragma unroll
            for (int j4 = 0; j4 < 4; j4++) {
                float4 q4 = *(const float4*)&qs[buf][s][dk0 + j4 * 4];
                S[j4 * 4 + 0] = eg * S[j4 * 4 + 0] + kk[j4].x * u;
                S[j4 * 4 + 1] = eg * S[j4 * 4 + 1] + kk[j4].y * u;
                S[j4 * 4 + 2] = eg * S[j4 * 4 + 2] + kk[j4].z * u;
                S[j4 * 4 + 3] = eg * S[j4 * 4 + 3] + kk[j4].w * u;
                oa.x += q4.x * S[j4 * 4 + 0];
                oa.y += q4.y * S[j4 * 4 + 1];
                oa.z += q4.z * S[j4 * 4 + 2];
                oa.w += q4.w * S[j4 * 4 + 3];
            }
            float ov = (oa.x + oa.y) + (oa.z + oa.w);
            ov += __shfl_xor(ov, 8);
            ov += __shfl_xor(ov, 16);
            ov += __shfl_xor(ov, 32);
            if (oct == 0) {
                o[((size_t)(b * T_ + c * CH + s)) * D_ + h * HD_ + col] = ov;
            }
        }
    };

    stage(0, 0);
    __syncthreads();
    for (int c = 0; c < T_ / CH; c++) {
        if (c + 1 < T_ / CH) stage(c + 1, (c + 1) & 1);
        computeC(c, c & 1);
        __syncthreads();
    }
    #pragma unroll
    for (int j = 0; j < 16; j++) {
        Sf[((size_t)bh * HD_ + (dk0 + j)) * HD_ + col] = S[j];
    }
}

// ---------------- gated per-head RMSNorm: og = rmsnorm(o)*onw * gate ----------------
// NOTE: gp already holds silu(h@gw) (applied in the GEMM epilogue) — no silu here.
__global__ __launch_bounds__(256) void gate_kernel(const float* __restrict__ o,
                                                   const unsigned short* __restrict__ gp,
                                                   const float* __restrict__ onw,
                                                   unsigned short* __restrict__ og) {
    int row = blockIdx.x * 4 + (threadIdx.x >> 6);
    int lane = threadIdx.x & 63;
    size_t base = (size_t)row * HD_ + lane * 2;
    float2 v = *(const float2*)(o + base);
    float a = v.x, b = v.y;
    float ss = a * a + b * b;
    #pragma unroll
    for (int m = 1; m < 64; m <<= 1) ss += __shfl_xor(ss, m);
    float sc = rsqrtf(ss * (1.f / HD_) + 1e-6f);
    unsigned int ug = *(const unsigned int*)(gp + base);
    float g0 = bf2f((unsigned short)(ug & 0xffffu)), g1 = bf2f((unsigned short)(ug >> 16));
    float w0 = onw[lane * 2], w1 = onw[lane * 2 + 1];
    float r0 = a * sc * w0 * g0;   // FIX: single silu (already in gp)
    float r1 = b * sc * w1 * g1;
    *(unsigned int*)(og + base) = ((unsigned int)f2bf(r1) << 16) | f2bf(r0);
}

extern "C" void kernel_launch(void* const* d_in, const int* in_sizes, int n_in,
                              void* d_out, int out_size, void* d_ws, size_t ws_size,
                              hipStream_t stream) {
    const float* x = (const float*)d_in[0];
    const float* ln1_w = (const float*)d_in[1];
    const float* qw = (const float*)d_in[2];
    const float* kw = (const float*)d_in[3];
    const float* vw = (const float*)d_in[4];
    const float* bw = (const float*)d_in[5];
    const float* aw = (const float*)d_in[6];
    const float* A_log = (const float*)d_in[7];
    const float* dt_bias = (const float*)d_in[8];
    const float* gw = (const float*)d_in[9];
    const float* onorm_w = (const float*)d_in[10];
    const float* ow = (const float*)d_in[11];
    const float* ln2_w = (const float*)d_in[12];
    const float* fcw = (const float*)d_in[13];
    const float* pw = (const float*)d_in[14];
    float* out = (float*)d_out;

    char* ws = (char*)d_ws;
    const size_t MB = 1024 * 1024;
    // weights 0..32MB
    unsigned short* WQh = (unsigned short*)(ws + 0 * MB);
    unsigned short* WQl = (unsigned short*)(ws + 2 * MB);
    unsigned short* WKh = (unsigned short*)(ws + 4 * MB);
    unsigned short* WKl = (unsigned short*)(ws + 6 * MB);
    unsigned short* WVh = (unsigned short*)(ws + 8 * MB);
    unsigned short* WVl = (unsigned short*)(ws + 10 * MB);
    unsigned short* WG  = (unsigned short*)(ws + 12 * MB);
    unsigned short* WO  = (unsigned short*)(ws + 14 * MB);
    unsigned short* WFC = (unsigned short*)(ws + 16 * MB);
    unsigned short* WP  = (unsigned short*)(ws + 24 * MB);
    // activations
    unsigned short* HBh = (unsigned short*)(ws + 32 * MB);   // 16 MB
    unsigned short* HBl = (unsigned short*)(ws + 48 * MB);   // 16 MB
    float*          QF  = (float*)(ws + 64 * MB);            // 32 MB (dead after scan)
    float*          KF  = (float*)(ws + 96 * MB);            // 32 MB (dead after scan)
    float*          VF  = (float*)(ws + 128 * MB);           // 32 MB (dead after scan)
    unsigned short* GPB = (unsigned short*)(ws + 160 * MB);  // 16 MB (dead after gate)
    float*          BETA= (float*)(ws + 176 * MB);           // 256 KB
    float*          GG  = (float*)(ws + 176 * MB + 262144);  // 256 KB (both dead after scan)
    float*          OF  = (float*)(ws + 177 * MB);           // 32 MB (dead after gate)
    // reuse
    unsigned short* OGB = (unsigned short*)(ws + 64 * MB);   // reuse QF, 16 MB
    float*          X1  = (float*)(ws + 96 * MB);            // reuse KF, 32 MB
    unsigned short* H2B = (unsigned short*)(ws + 160 * MB);  // reuse GPB, 16 MB
    unsigned short* MID = (unsigned short*)(ws + 176 * MB);  // reuse BETA/GG/OF, 64 MB -> peak 240 MB

    // weight conversions
    cvt2_kernel<<<1024, 256, 0, stream>>>(qw, WQh, WQl, 262144);
    cvt2_kernel<<<1024, 256, 0, stream>>>(kw, WKh, WKl, 262144);
    cvt2_kernel<<<1024, 256, 0, stream>>>(vw, WVh, WVl, 262144);
    cvt_kernel<<<1024, 256, 0, stream>>>(gw, WG, 262144);
    cvt_kernel<<<1024, 256, 0, stream>>>(ow, WO, 262144);
    cvt_kernel<<<4096, 256, 0, stream>>>(fcw, WFC, 1048576);
    cvt_kernel<<<4096, 256, 0, stream>>>(pw, WP, 1048576);

    // h = rmsnorm(x, ln1_w) -> hi+lo planes
    rmsnorm_kernel<<<8192, 256, 0, stream>>>(x, ln1_w, HBh, HBl);

    // q/k/v: split-bf16 3-pass GEMM, silu -> f32
    gemm32_kernel<<<dim3(64, 8), 256, 0, stream>>>(HBh, HBl, WQh, WQl, QF, 1024, 1024);
    gemm32_kernel<<<dim3(64, 8), 256, 0, stream>>>(HBh, HBl, WKh, WKl, KF, 1024, 1024);
    gemm32_kernel<<<dim3(64, 8), 256, 0, stream>>>(HBh, HBl, WVh, WVl, VF, 1024, 1024);
    // gate proj: plain bf16, silu applied here (once)
    gemm_kernel<<<dim3(64, 8), 256, 0, stream>>>(HBh, WG, GPB, nullptr, nullptr, 1024, 1024, 0);

    // beta/g from fp32 h
    smallproj_kernel<<<8192, 256, 0, stream>>>(HBh, HBl, bw, aw, A_log, dt_bias, BETA, GG);

    l2norm_kernel<<<16384, 256, 0, stream>>>(QF);
    l2norm_kernel<<<16384, 256, 0, stream>>>(KF);

    // scan: o (f32) + final state -> d_out tail (f32)
    scan_kernel<<<64, 512, 0, stream>>>(QF, KF, VF, BETA, GG, OF, out + 8388608);

    gate_kernel<<<16384, 256, 0, stream>>>(OF, GPB, onorm_w, OGB);

    // x1 = x + (og @ ow) * 0.5
    gemm_kernel<<<dim3(64, 8), 256, 0, stream>>>(OGB, WO, nullptr, X1, x, 1024, 1024, 1);

    // h2 = rmsnorm(x1, ln2_w) (bf16 only)
    rmsnorm_kernel<<<8192, 256, 0, stream>>>(X1, ln2_w, H2B, nullptr);

    // mid = silu(h2 @ fcw)
    gemm_kernel<<<dim3(64, 32), 256, 0, stream>>>(H2B, WFC, MID, nullptr, nullptr, 4096, 1024, 0);

    // y = x1 + (mid @ pw) * 0.5
    gemm_kernel<<<dim3(64, 8), 256, 0, stream>>>(MID, WP, nullptr, out, X1, 1024, 4096, 1);
}

// Round 8
// 2546.055 us; speedup vs baseline: 1.1018x; 1.1018x over previous
//
#include <hip/hip_runtime.h>
#include <math.h>

// GatedDeltaBlock on MI355X (gfx950). Round 8.
// r7 PASSED (absmax 0.031). This round: speed.
//  - q/k/v/gate projections fused into ONE plain-bf16 MFMA GEMM (N=4096);
//    r1-vs-r4 bit-identical absmax proved split-bf16 precision was unneeded.
//  - scan: XOR bank-swizzle (slot^=slot>>3) on k/q LDS rows (4-way -> 0 conflict),
//    kr as 4-partial tree instead of 16-deep dependent FMA chain.

#define B_ 4
#define T_ 2048
#define D_ 1024
#define H_ 8
#define HD_ 128
#define RES_SCALE 0.5f

typedef __bf16 bf16x8 __attribute__((ext_vector_type(8)));
typedef float f32x4 __attribute__((ext_vector_type(4)));

__device__ __forceinline__ float bf2f(unsigned short u) {
    union { unsigned int i; float f; } w; w.i = ((unsigned int)u) << 16; return w.f;
}
__device__ __forceinline__ unsigned short f2bf(float f) {
    unsigned int x = __float_as_uint(f);
    x += 0x7fffu + ((x >> 16) & 1u);   // RNE
    return (unsigned short)(x >> 16);
}
__device__ __forceinline__ float sigm(float x) { return 1.f / (1.f + __expf(-x)); }

// ---------------- f32 -> bf16 ----------------
__global__ __launch_bounds__(256) void cvt_kernel(const float* __restrict__ src,
                                                  unsigned short* __restrict__ dst, int n4) {
    int i = blockIdx.x * 256 + threadIdx.x;
    if (i < n4) {
        float4 v = ((const float4*)src)[i];
        ushort4 o;
        o.x = f2bf(v.x); o.y = f2bf(v.y); o.z = f2bf(v.z); o.w = f2bf(v.w);
        ((ushort4*)dst)[i] = o;
    }
}

// ---------------- f32 [1024x1024] -> bf16 column block of [1024x4096] ----------------
__global__ __launch_bounds__(256) void cvtw_kernel(const float* __restrict__ src,
                                                   unsigned short* __restrict__ dst, int colofs) {
    int i = blockIdx.x * 256 + threadIdx.x;   // 262144 float4s
    if (i < 262144) {
        float4 v = ((const float4*)src)[i];
        int s4 = i * 4;
        int srow = s4 >> 10, scol = s4 & 1023;
        ushort4 o;
        o.x = f2bf(v.x); o.y = f2bf(v.y); o.z = f2bf(v.z); o.w = f2bf(v.w);
        *(ushort4*)(dst + (size_t)srow * 4096 + colofs + scol) = o;
    }
}

// ---------------- RMSNorm (D=1024), f32 in -> bf16 hi (+ optional lo) ----------------
__global__ __launch_bounds__(256) void rmsnorm_kernel(const float* __restrict__ x,
                                                      const float* __restrict__ w,
                                                      unsigned short* __restrict__ outh,
                                                      unsigned short* __restrict__ outl) {
    int row = blockIdx.x;
    int tid = threadIdx.x;
    float4 v = ((const float4*)(x + (size_t)row * D_))[tid];
    float ss = v.x * v.x + v.y * v.y + v.z * v.z + v.w * v.w;
    #pragma unroll
    for (int m = 1; m < 64; m <<= 1) ss += __shfl_xor(ss, m);
    __shared__ float red[4];
    if ((tid & 63) == 0) red[tid >> 6] = ss;
    __syncthreads();
    float tot = red[0] + red[1] + red[2] + red[3];
    float sc = rsqrtf(tot * (1.f / D_) + 1e-6f);
    float4 wv = ((const float4*)w)[tid];
    float h0 = v.x * sc * wv.x, h1 = v.y * sc * wv.y;
    float h2 = v.z * sc * wv.z, h3 = v.w * sc * wv.w;
    ushort4 oh;
    oh.x = f2bf(h0); oh.y = f2bf(h1); oh.z = f2bf(h2); oh.w = f2bf(h3);
    ((ushort4*)(outh + (size_t)row * D_))[tid] = oh;
    if (outl) {
        ushort4 ol;
        ol.x = f2bf(h0 - bf2f(oh.x));
        ol.y = f2bf(h1 - bf2f(oh.y));
        ol.z = f2bf(h2 - bf2f(oh.z));
        ol.w = f2bf(h3 - bf2f(oh.w));
        ((ushort4*)(outl + (size_t)row * D_))[tid] = ol;
    }
}

// ---------------- plain bf16 MFMA GEMM ----------------
// 128x128 tile, BK=32, 256 thr. epi 0: silu->bf16. epi 1: f32 = aux + acc*0.5.
#define LDT 40
__global__ __launch_bounds__(256) void gemm_kernel(const unsigned short* __restrict__ A,
                                                   const unsigned short* __restrict__ Bm,
                                                   unsigned short* __restrict__ Obf,
                                                   float* __restrict__ Of,
                                                   const float* __restrict__ aux,
                                                   int N, int K, int epi) {
    __shared__ unsigned short As[128 * LDT];
    __shared__ unsigned short Bs[128 * LDT];
    int tid = threadIdx.x;
    int lane = tid & 63, wave = tid >> 6;
    int wm = (wave >> 1) * 64, wn = (wave & 1) * 64;
    int l15 = lane & 15, kg = lane >> 4;
    size_t gm = blockIdx.x, gn = blockIdx.y;

    int arow0 = tid >> 2, aseg = (tid & 3) * 8;
    int brow0 = tid >> 4, bc8 = (tid & 15) * 8;

    f32x4 acc[4][4] = {};

    for (int kt = 0; kt < K; kt += 32) {
        uint4 a0 = *(const uint4*)(A + (size_t)(gm * 128 + arow0) * K + kt + aseg);
        uint4 a1 = *(const uint4*)(A + (size_t)(gm * 128 + arow0 + 64) * K + kt + aseg);
        uint4 b0 = *(const uint4*)(Bm + (size_t)(kt + brow0) * N + gn * 128 + bc8);
        uint4 b1 = *(const uint4*)(Bm + (size_t)(kt + brow0 + 16) * N + gn * 128 + bc8);
        __syncthreads();
        *(uint4*)&As[arow0 * LDT + aseg] = a0;
        *(uint4*)&As[(arow0 + 64) * LDT + aseg] = a1;
        {
            unsigned int uu[4] = {b0.x, b0.y, b0.z, b0.w};
            #pragma unroll
            for (int p = 0; p < 4; p++) {
                Bs[(bc8 + 2 * p) * LDT + brow0] = (unsigned short)(uu[p] & 0xffffu);
                Bs[(bc8 + 2 * p + 1) * LDT + brow0] = (unsigned short)(uu[p] >> 16);
            }
            unsigned int vv[4] = {b1.x, b1.y, b1.z, b1.w};
            #pragma unroll
            for (int p = 0; p < 4; p++) {
                Bs[(bc8 + 2 * p) * LDT + brow0 + 16] = (unsigned short)(vv[p] & 0xffffu);
                Bs[(bc8 + 2 * p + 1) * LDT + brow0 + 16] = (unsigned short)(vv[p] >> 16);
            }
        }
        __syncthreads();
        bf16x8 af[4], bfr[4];
        #pragma unroll
        for (int m = 0; m < 4; m++)
            af[m] = *(const bf16x8*)&As[(wm + m * 16 + l15) * LDT + kg * 8];
        #pragma unroll
        for (int n = 0; n < 4; n++)
            bfr[n] = *(const bf16x8*)&Bs[(wn + n * 16 + l15) * LDT + kg * 8];
        #pragma unroll
        for (int m = 0; m < 4; m++)
            #pragma unroll
            for (int n = 0; n < 4; n++)
                acc[m][n] = __builtin_amdgcn_mfma_f32_16x16x32_bf16(af[m], bfr[n], acc[m][n], 0, 0, 0);
    }

    #pragma unroll
    for (int m = 0; m < 4; m++) {
        #pragma unroll
        for (int n = 0; n < 4; n++) {
            #pragma unroll
            for (int j = 0; j < 4; j++) {
                size_t row = gm * 128 + wm + m * 16 + kg * 4 + j;
                size_t col = gn * 128 + wn + n * 16 + l15;
                size_t idx = row * N + col;
                float v = acc[m][n][j];
                if (epi == 0) {
                    Obf[idx] = f2bf(v * sigm(v));
                } else {
                    Of[idx] = aux[idx] + v * RES_SCALE;
                }
            }
        }
    }
}

// ---------------- fused qkvg GEMM: [8192x1024] @ [1024x4096] ----------------
// gn 0-7 -> q (silu, f32), 8-15 -> k, 16-23 -> v, 24-31 -> gate (silu, bf16)
__global__ __launch_bounds__(256) void gemm_qkvg_kernel(const unsigned short* __restrict__ A,
                                                        const unsigned short* __restrict__ Bm,
                                                        float* __restrict__ Qo,
                                                        float* __restrict__ Ko,
                                                        float* __restrict__ Vo,
                                                        unsigned short* __restrict__ Go) {
    const int N = 4096, K = 1024;
    __shared__ unsigned short As[128 * LDT];
    __shared__ unsigned short Bs[128 * LDT];
    int tid = threadIdx.x;
    int lane = tid & 63, wave = tid >> 6;
    int wm = (wave >> 1) * 64, wn = (wave & 1) * 64;
    int l15 = lane & 15, kg = lane >> 4;
    size_t gm = blockIdx.x, gn = blockIdx.y;

    int arow0 = tid >> 2, aseg = (tid & 3) * 8;
    int brow0 = tid >> 4, bc8 = (tid & 15) * 8;

    f32x4 acc[4][4] = {};

    for (int kt = 0; kt < K; kt += 32) {
        uint4 a0 = *(const uint4*)(A + (size_t)(gm * 128 + arow0) * K + kt + aseg);
        uint4 a1 = *(const uint4*)(A + (size_t)(gm * 128 + arow0 + 64) * K + kt + aseg);
        uint4 b0 = *(const uint4*)(Bm + (size_t)(kt + brow0) * N + gn * 128 + bc8);
        uint4 b1 = *(const uint4*)(Bm + (size_t)(kt + brow0 + 16) * N + gn * 128 + bc8);
        __syncthreads();
        *(uint4*)&As[arow0 * LDT + aseg] = a0;
        *(uint4*)&As[(arow0 + 64) * LDT + aseg] = a1;
        {
            unsigned int uu[4] = {b0.x, b0.y, b0.z, b0.w};
            #pragma unroll
            for (int p = 0; p < 4; p++) {
                Bs[(bc8 + 2 * p) * LDT + brow0] = (unsigned short)(uu[p] & 0xffffu);
                Bs[(bc8 + 2 * p + 1) * LDT + brow0] = (unsigned short)(uu[p] >> 16);
            }
            unsigned int vv[4] = {b1.x, b1.y, b1.z, b1.w};
            #pragma unroll
            for (int p = 0; p < 4; p++) {
                Bs[(bc8 + 2 * p) * LDT + brow0 + 16] = (unsigned short)(vv[p] & 0xffffu);
                Bs[(bc8 + 2 * p + 1) * LDT + brow0 + 16] = (unsigned short)(vv[p] >> 16);
            }
        }
        __syncthreads();
        bf16x8 af[4], bfr[4];
        #pragma unroll
        for (int m = 0; m < 4; m++)
            af[m] = *(const bf16x8*)&As[(wm + m * 16 + l15) * LDT + kg * 8];
        #pragma unroll
        for (int n = 0; n < 4; n++)
            bfr[n] = *(const bf16x8*)&Bs[(wn + n * 16 + l15) * LDT + kg * 8];
        #pragma unroll
        for (int m = 0; m < 4; m++)
            #pragma unroll
            for (int n = 0; n < 4; n++)
                acc[m][n] = __builtin_amdgcn_mfma_f32_16x16x32_bf16(af[m], bfr[n], acc[m][n], 0, 0, 0);
    }

    int sel = (int)(gn >> 3);                 // 0=q 1=k 2=v 3=g
    int colbase = (int)(gn & 7) * 128;
    float* fo = (sel == 0) ? Qo : (sel == 1) ? Ko : Vo;
    #pragma unroll
    for (int m = 0; m < 4; m++) {
        #pragma unroll
        for (int n = 0; n < 4; n++) {
            #pragma unroll
            for (int j = 0; j < 4; j++) {
                size_t row = gm * 128 + wm + m * 16 + kg * 4 + j;
                size_t col = colbase + wn + n * 16 + l15;
                float v = acc[m][n][j];
                float s = v * sigm(v);
                if (sel < 3) fo[row * 1024 + col] = s;
                else Go[row * 1024 + col] = f2bf(s);
            }
        }
    }
}

// ---------------- beta / g projections from fp32 h (hi+lo) ----------------
__global__ __launch_bounds__(256) void smallproj_kernel(const unsigned short* __restrict__ hh,
                                                        const unsigned short* __restrict__ hl,
                                                        const float* __restrict__ bw,
                                                        const float* __restrict__ aw,
                                                        const float* __restrict__ A_log,
                                                        const float* __restrict__ dt_bias,
                                                        float* __restrict__ beta,
                                                        float* __restrict__ g) {
    int row = blockIdx.x;
    int tid = threadIdx.x;
    int out = tid >> 4, part = tid & 15;   // 16 outputs x 16 partials
    int head = out & 7;
    const float* W = (out < 8) ? bw : aw;
    const unsigned short* hrh = hh + (size_t)row * D_ + part * 64;
    const unsigned short* hrl = hl + (size_t)row * D_ + part * 64;
    float s = 0.f;
    #pragma unroll
    for (int j8 = 0; j8 < 8; j8++) {
        uint4 uh = *(const uint4*)(hrh + j8 * 8);
        uint4 ul = *(const uint4*)(hrl + j8 * 8);
        unsigned int ah[4] = {uh.x, uh.y, uh.z, uh.w};
        unsigned int al[4] = {ul.x, ul.y, ul.z, ul.w};
        #pragma unroll
        for (int p = 0; p < 4; p++) {
            int k = part * 64 + j8 * 8 + 2 * p;
            float v0 = bf2f((unsigned short)(ah[p] & 0xffffu)) + bf2f((unsigned short)(al[p] & 0xffffu));
            float v1 = bf2f((unsigned short)(ah[p] >> 16)) + bf2f((unsigned short)(al[p] >> 16));
            s += v0 * W[(size_t)k * H_ + head];
            s += v1 * W[(size_t)(k + 1) * H_ + head];
        }
    }
    s += __shfl_xor(s, 1); s += __shfl_xor(s, 2); s += __shfl_xor(s, 4); s += __shfl_xor(s, 8);
    if (part == 0) {
        if (out < 8) {
            beta[(size_t)row * H_ + head] = sigm(s);
        } else {
            float xx = s + dt_bias[head];
            float sp = (xx > 20.f) ? xx : log1pf(expf(xx));
            g[(size_t)row * H_ + head] = -expf(A_log[head]) * sp;
        }
    }
}

// ---------------- l2norm over HD=128, in-place on f32 ----------------
__global__ __launch_bounds__(256) void l2norm_kernel(float* __restrict__ qk) {
    int row = blockIdx.x * 4 + (threadIdx.x >> 6);
    int lane = threadIdx.x & 63;
    float* r = qk + (size_t)row * HD_ + lane * 2;
    float2 v = *(const float2*)r;
    float ss = v.x * v.x + v.y * v.y;
    #pragma unroll
    for (int m = 1; m < 64; m <<= 1) ss += __shfl_xor(ss, m);
    float sc = rsqrtf(ss + 1e-6f);
    float2 o = {v.x * sc, v.y * sc};
    *(float2*)r = o;
}

// ---------------- recurrent scan (fp32), bank-swizzled k/q LDS ----------------
// k/q rows stored as 32 float4-slots with slot' = slot ^ (slot>>3): per-instruction
// reads across the 8 octs land on 8 distinct bank quads (0 conflicts).
#define CH 32
__global__ __launch_bounds__(512) void scan_kernel(const float* __restrict__ q,
                                                   const float* __restrict__ k,
                                                   const float* __restrict__ v,
                                                   const float* __restrict__ beta,
                                                   const float* __restrict__ g,
                                                   float* __restrict__ o,
                                                   float* __restrict__ Sf) {
    int bh = blockIdx.x >> 1;
    int b = bh >> 3, h = bh & 7;
    int cb = (blockIdx.x & 1) * 64;
    int tid = threadIdx.x;
    int wave = tid >> 6, lane = tid & 63;
    int col = cb + wave * 8 + (lane & 7);
    int oct = lane >> 3;
    int dk0 = oct * 16;

    __shared__ float ks[2][CH][HD_];
    __shared__ float qs[2][CH][HD_];
    __shared__ float vs[2][CH][HD_];
    __shared__ float egs[2][CH];
    __shared__ float bes[2][CH];

    float S[16];
    #pragma unroll
    for (int j = 0; j < 16; j++) S[j] = 0.f;

    int sstep = tid >> 4;          // 0..31
    int slot0 = (tid & 15) * 2;    // staging float4-slot
    int sd = slot0 * 4;
    int sw0 = (slot0 ^ (slot0 >> 3)) << 2;
    int sw1 = ((slot0 + 1) ^ ((slot0 + 1) >> 3)) << 2;

    // per-thread swizzled read offsets for the 4 dk segments
    int ro[4];
    #pragma unroll
    for (int j4 = 0; j4 < 4; j4++) {
        int sl = oct * 4 + j4;
        ro[j4] = (sl ^ (sl >> 3)) << 2;
    }

    auto stage = [&](int c, int buf) {
        size_t gbase = ((size_t)(b * T_ + c * CH + sstep)) * D_ + h * HD_ + sd;
        float4 q0 = *(const float4*)(q + gbase);
        float4 q1 = *(const float4*)(q + gbase + 4);
        float4 k0 = *(const float4*)(k + gbase);
        float4 k1 = *(const float4*)(k + gbase + 4);
        float4 v0 = *(const float4*)(v + gbase);
        float4 v1 = *(const float4*)(v + gbase + 4);
        *(float4*)&qs[buf][sstep][sw0] = q0;
        *(float4*)&qs[buf][sstep][sw1] = q1;
        *(float4*)&ks[buf][sstep][sw0] = k0;
        *(float4*)&ks[buf][sstep][sw1] = k1;
        *(float4*)&vs[buf][sstep][sd] = v0;
        *(float4*)&vs[buf][sstep][sd + 4] = v1;
        if (tid < CH) {
            egs[buf][tid] = expf(g[(size_t)(b * T_ + c * CH + tid) * H_ + h]);
        } else if (tid < 2 * CH) {
            bes[buf][tid - CH] = beta[(size_t)(b * T_ + c * CH + (tid - CH)) * H_ + h];
        }
    };

    auto computeC = [&](int c, int buf) {
        for (int s = 0; s < CH; s++) {
            float eg = egs[buf][s];
            float be = bes[buf][s];
            float vv = vs[buf][s][col];
            float4 kk0 = *(const float4*)&ks[buf][s][ro[0]];
            float4 kk1 = *(const float4*)&ks[buf][s][ro[1]];
            float4 kk2 = *(const float4*)&ks[buf][s][ro[2]];
            float4 kk3 = *(const float4*)&ks[buf][s][ro[3]];
            float4 qq0 = *(const float4*)&qs[buf][s][ro[0]];
            float4 qq1 = *(const float4*)&qs[buf][s][ro[1]];
            float4 qq2 = *(const float4*)&qs[buf][s][ro[2]];
            float4 qq3 = *(const float4*)&qs[buf][s][ro[3]];
            // kr: 4 independent partials, tree combine (shortens dep chain 64->~30 cyc)
            float p0 = ((kk0.x * S[0] + kk0.y * S[1]) + (kk0.z * S[2] + kk0.w * S[3]));
            float p1 = ((kk1.x * S[4] + kk1.y * S[5]) + (kk1.z * S[6] + kk1.w * S[7]));
            float p2 = ((kk2.x * S[8] + kk2.y * S[9]) + (kk2.z * S[10] + kk2.w * S[11]));
            float p3 = ((kk3.x * S[12] + kk3.y * S[13]) + (kk3.z * S[14] + kk3.w * S[15]));
            float kr = (p0 + p1) + (p2 + p3);
            kr += __shfl_xor(kr, 8);
            kr += __shfl_xor(kr, 16);
            kr += __shfl_xor(kr, 32);
            float u = be * (vv - eg * kr);
            S[0] = eg * S[0] + kk0.x * u;  S[1] = eg * S[1] + kk0.y * u;
            S[2] = eg * S[2] + kk0.z * u;  S[3] = eg * S[3] + kk0.w * u;
            S[4] = eg * S[4] + kk1.x * u;  S[5] = eg * S[5] + kk1.y * u;
            S[6] = eg * S[6] + kk1.z * u;  S[7] = eg * S[7] + kk1.w * u;
            S[8] = eg * S[8] + kk2.x * u;  S[9] = eg * S[9] + kk2.y * u;
            S[10] = eg * S[10] + kk2.z * u; S[11] = eg * S[11] + kk2.w * u;
            S[12] = eg * S[12] + kk3.x * u; S[13] = eg * S[13] + kk3.y * u;
            S[14] = eg * S[14] + kk3.z * u; S[15] = eg * S[15] + kk3.w * u;
            float oa0 = ((qq0.x * S[0] + qq0.y * S[1]) + (qq0.z * S[2] + qq0.w * S[3]));
            float oa1 = ((qq1.x * S[4] + qq1.y * S[5]) + (qq1.z * S[6] + qq1.w * S[7]));
            float oa2 = ((qq2.x * S[8] + qq2.y * S[9]) + (qq2.z * S[10] + qq2.w * S[11]));
            float oa3 = ((qq3.x * S[12] + qq3.y * S[13]) + (qq3.z * S[14] + qq3.w * S[15]));
            float ov = (oa0 + oa1) + (oa2 + oa3);
            ov += __shfl_xor(ov, 8);
            ov += __shfl_xor(ov, 16);
            ov += __shfl_xor(ov, 32);
            if (oct == 0) {
                o[((size_t)(b * T_ + c * CH + s)) * D_ + h * HD_ + col] = ov;
            }
        }
    };

    stage(0, 0);
    __syncthreads();
    for (int c = 0; c < T_ / CH; c++) {
        if (c + 1 < T_ / CH) stage(c + 1, (c + 1) & 1);
        computeC(c, c & 1);
        __syncthreads();
    }
    #pragma unroll
    for (int j = 0; j < 16; j++) {
        Sf[((size_t)bh * HD_ + (dk0 + j)) * HD_ + col] = S[j];
    }
}

// ---------------- gated per-head RMSNorm: og = rmsnorm(o)*onw * gate ----------------
// gp already holds silu(h@gw) (applied in the GEMM epilogue).
__global__ __launch_bounds__(256) void gate_kernel(const float* __restrict__ o,
                                                   const unsigned short* __restrict__ gp,
                                                   const float* __restrict__ onw,
                                                   unsigned short* __restrict__ og) {
    int row = blockIdx.x * 4 + (threadIdx.x >> 6);
    int lane = threadIdx.x & 63;
    size_t base = (size_t)row * HD_ + lane * 2;
    float2 v = *(const float2*)(o + base);
    float a = v.x, b = v.y;
    float ss = a * a + b * b;
    #pragma unroll
    for (int m = 1; m < 64; m <<= 1) ss += __shfl_xor(ss, m);
    float sc = rsqrtf(ss * (1.f / HD_) + 1e-6f);
    unsigned int ug = *(const unsigned int*)(gp + base);
    float g0 = bf2f((unsigned short)(ug & 0xffffu)), g1 = bf2f((unsigned short)(ug >> 16));
    float w0 = onw[lane * 2], w1 = onw[lane * 2 + 1];
    float r0 = a * sc * w0 * g0;
    float r1 = b * sc * w1 * g1;
    *(unsigned int*)(og + base) = ((unsigned int)f2bf(r1) << 16) | f2bf(r0);
}

extern "C" void kernel_launch(void* const* d_in, const int* in_sizes, int n_in,
                              void* d_out, int out_size, void* d_ws, size_t ws_size,
                              hipStream_t stream) {
    const float* x = (const float*)d_in[0];
    const float* ln1_w = (const float*)d_in[1];
    const float* qw = (const float*)d_in[2];
    const float* kw = (const float*)d_in[3];
    const float* vw = (const float*)d_in[4];
    const float* bw = (const float*)d_in[5];
    const float* aw = (const float*)d_in[6];
    const float* A_log = (const float*)d_in[7];
    const float* dt_bias = (const float*)d_in[8];
    const float* gw = (const float*)d_in[9];
    const float* onorm_w = (const float*)d_in[10];
    const float* ow = (const float*)d_in[11];
    const float* ln2_w = (const float*)d_in[12];
    const float* fcw = (const float*)d_in[13];
    const float* pw = (const float*)d_in[14];
    float* out = (float*)d_out;

    char* ws = (char*)d_ws;
    const size_t MB = 1024 * 1024;
    // weights
    unsigned short* WALL = (unsigned short*)(ws + 0 * MB);   // qkvg fused [1024x4096], 8 MB
    unsigned short* WO   = (unsigned short*)(ws + 8 * MB);   // 2 MB
    unsigned short* WFC  = (unsigned short*)(ws + 10 * MB);  // 8 MB
    unsigned short* WP   = (unsigned short*)(ws + 18 * MB);  // 8 MB
    // activations
    unsigned short* HBh = (unsigned short*)(ws + 26 * MB);   // 16 MB
    unsigned short* HBl = (unsigned short*)(ws + 42 * MB);   // 16 MB
    float*          QF  = (float*)(ws + 58 * MB);            // 32 MB (dead after scan)
    float*          KF  = (float*)(ws + 90 * MB);            // 32 MB (dead after scan)
    float*          VF  = (float*)(ws + 122 * MB);           // 32 MB (dead after scan)
    unsigned short* GPB = (unsigned short*)(ws + 154 * MB);  // 16 MB (dead after gate)
    float*          BETA= (float*)(ws + 170 * MB);           // 256 KB
    float*          GG  = (float*)(ws + 170 * MB + 262144);  // 256 KB
    float*          OF  = (float*)(ws + 171 * MB);           // 32 MB (dead after gate)
    // reuse
    unsigned short* OGB = (unsigned short*)(ws + 58 * MB);   // reuse QF, 16 MB
    float*          X1  = (float*)(ws + 90 * MB);            // reuse KF, 32 MB
    unsigned short* H2B = (unsigned short*)(ws + 154 * MB);  // reuse GPB, 16 MB
    unsigned short* MID = (unsigned short*)(ws + 171 * MB);  // reuse OF+, 64 MB -> peak 235 MB

    // weight conversions: q/k/v/g -> one [1024x4096] bf16 matrix
    cvtw_kernel<<<1024, 256, 0, stream>>>(qw, WALL, 0);
    cvtw_kernel<<<1024, 256, 0, stream>>>(kw, WALL, 1024);
    cvtw_kernel<<<1024, 256, 0, stream>>>(vw, WALL, 2048);
    cvtw_kernel<<<1024, 256, 0, stream>>>(gw, WALL, 3072);
    cvt_kernel<<<1024, 256, 0, stream>>>(ow, WO, 262144);
    cvt_kernel<<<4096, 256, 0, stream>>>(fcw, WFC, 1048576);
    cvt_kernel<<<4096, 256, 0, stream>>>(pw, WP, 1048576);

    // h = rmsnorm(x, ln1_w) -> bf16 hi (+ lo for beta/g precision)
    rmsnorm_kernel<<<8192, 256, 0, stream>>>(x, ln1_w, HBh, HBl);

    // fused q/k/v/gate projection (silu epilogue; q/k/v f32, gate bf16)
    gemm_qkvg_kernel<<<dim3(64, 32), 256, 0, stream>>>(HBh, WALL, QF, KF, VF, GPB);

    // beta/g from fp32 h
    smallproj_kernel<<<8192, 256, 0, stream>>>(HBh, HBl, bw, aw, A_log, dt_bias, BETA, GG);

    l2norm_kernel<<<16384, 256, 0, stream>>>(QF);
    l2norm_kernel<<<16384, 256, 0, stream>>>(KF);

    // scan: o (f32) + final state -> d_out tail (f32)
    scan_kernel<<<64, 512, 0, stream>>>(QF, KF, VF, BETA, GG, OF, out + 8388608);

    gate_kernel<<<16384, 256, 0, stream>>>(OF, GPB, onorm_w, OGB);

    // x1 = x + (og @ ow) * 0.5
    gemm_kernel<<<dim3(64, 8), 256, 0, stream>>>(OGB, WO, nullptr, X1, x, 1024, 1024, 1);

    // h2 = rmsnorm(x1, ln2_w) (bf16 only)
    rmsnorm_kernel<<<8192, 256, 0, stream>>>(X1, ln2_w, H2B, nullptr);

    // mid = silu(h2 @ fcw)
    gemm_kernel<<<dim3(64, 32), 256, 0, stream>>>(H2B, WFC, MID, nullptr, nullptr, 4096, 1024, 0);

    // y = x1 + (mid @ pw) * 0.5
    gemm_kernel<<<dim3(64, 8), 256, 0, stream>>>(MID, WP, nullptr, out, X1, 1024, 4096, 1);
}